// Round 6
// baseline (488.782 us; speedup 1.0000x reference)
//
#include <hip/hip_runtime.h>

#define L_DIM 2048
#define C_DIM 512
#define B_DIM 8

typedef __attribute__((ext_vector_type(8))) short bf16x8;   // 8 bf16 = 4 VGPR
typedef __attribute__((ext_vector_type(4))) float f32x4;    // MFMA acc

constexpr size_t SQ  = (size_t)L_DIM * C_DIM;   // per-batch q/k/v stride
constexpr size_t SAT = (size_t)L_DIM * L_DIM;   // per-batch attn stride

__device__ __forceinline__ float bf2f(ushort u) {
  union { float f; unsigned int i; } c; c.i = ((unsigned int)u) << 16; return c.f;
}
__device__ __forceinline__ ushort f2bf(float f) {
  union { float f; unsigned int i; } c; c.f = f;
  unsigned int lsb = (c.i >> 16) & 1u;
  return (ushort)((c.i + 0x7FFFu + lsb) >> 16);
}

__device__ __forceinline__ float wave_red_max(float v) {
  #pragma unroll
  for (int o = 1; o < 64; o <<= 1) v = fmaxf(v, __shfl_xor(v, o, 64));
  return v;
}
__device__ __forceinline__ float wave_red_sum(float v) {
  #pragma unroll
  for (int o = 1; o < 64; o <<= 1) v += __shfl_xor(v, o, 64);
  return v;
}

// async global->LDS, 16B per lane (dest = wave-uniform base + lane*16)
__device__ __forceinline__ void glds16(const ushort* g, ushort* l) {
  __builtin_amdgcn_global_load_lds(
      (const __attribute__((address_space(1))) void*)g,
      (__attribute__((address_space(3))) void*)l, 16, 0, 0);
}

// ---------------------------------------------------------------------------
// 256x256 bf16 MFMA GEMM core, D = A.B^T. BK=64, 512 thr = 8 waves (2M x 4N),
// wave tile 128x64 (8x4 fragments). Double-buffered LDS (2 x 64 KiB),
// prefetch-before-compute. A: [m][K] (lda), B: [n][K] (ldb).
// K-tile LDS: row r (128 B) holds 16B-chunks at slot s = chunk ^ (r&7),
// achieved with linear glds dest + inverse-swizzled global source.
// EPI: 0 row-major store, 1 transposed store, 2 both (bf16, via LDS C-bounce
// in two 128-row halves; C-bounce slot swizzle = (c>>3) ^ (r&15)).
// ---------------------------------------------------------------------------
__device__ __forceinline__ void gemm_core256(
    const ushort* __restrict__ Ab, const ushort* __restrict__ Bb,
    const float* __restrict__ bias,
    ushort* __restrict__ obN, ushort* __restrict__ obT,
    const int K, const int lda, const int ldb, const int ldo, const int ldoT,
    const int m0, const int n0, const float scale, const int EPI)
{
  __shared__ __align__(16) ushort lds[65536];   // 128 KiB: buf b at b*32768 (A 16K | B 16K ushorts)

  const int t = threadIdx.x;
  const int lane = t & 63, w = t >> 6;        // 8 waves
  const int wr = w >> 2, wc = w & 3;          // 2 x 4 wave grid
  const int l16 = lane & 15, lhi = lane >> 4;
  const int lrow = lane >> 3, lsl = lane & 7;

  f32x4 acc[8][4];
  #pragma unroll
  for (int i = 0; i < 8; ++i)
    #pragma unroll
    for (int j = 0; j < 4; ++j) { f32x4 zv = {0.f, 0.f, 0.f, 0.f}; acc[i][j] = zv; }

  auto stage = [&](int buf, int k0) {
    ushort* dstA = lds + buf * 32768 + w * 2048;     // wave w: rows w*32..w*32+31
    ushort* dstB = dstA + 16384;
    #pragma unroll
    for (int p = 0; p < 4; ++p) {
      const int rr = w * 32 + p * 8 + lrow;
      const int ch = lsl ^ (rr & 7);
      glds16(Ab + (size_t)(m0 + rr) * lda + k0 + ch * 8, dstA + p * 512);
      glds16(Bb + (size_t)(n0 + rr) * ldb + k0 + ch * 8, dstB + p * 512);
    }
  };

  const int KT = K >> 6;
  stage(0, 0);
  __syncthreads();                           // drains vmcnt -> buf0 ready
  int cur = 0;
  for (int kt = 0; kt < KT; ++kt) {
    if (kt + 1 < KT) stage(cur ^ 1, (kt + 1) << 6);  // flies under compute
    const ushort* As = lds + cur * 32768;
    const ushort* Bs = As + 16384;
    #pragma unroll
    for (int ks = 0; ks < 2; ++ks) {
      bf16x8 bg[4];
      #pragma unroll
      for (int j = 0; j < 4; ++j) {
        const int rb = wc * 64 + j * 16 + l16;
        bg[j] = *(const bf16x8*)&Bs[rb * 64 + 8 * ((ks * 4 + lhi) ^ (rb & 7))];
      }
      #pragma unroll
      for (int i = 0; i < 8; ++i) {
        const int ra = wr * 128 + i * 16 + l16;
        const bf16x8 af = *(const bf16x8*)&As[ra * 64 + 8 * ((ks * 4 + lhi) ^ (ra & 7))];
        #pragma unroll
        for (int j = 0; j < 4; ++j)
          acc[i][j] = __builtin_amdgcn_mfma_f32_16x16x32_bf16(af, bg[j], acc[i][j], 0, 0, 0);
      }
    }
    __syncthreads();   // all waves done with buf[cur]; prefetch landed
    cur ^= 1;
  }

  // ---- epilogue: bounce C (256x256 bf16) through LDS in two 128-row halves
  ushort* Cs = lds;    // 128 x 256 bf16 = 64 KiB
  for (int h = 0; h < 2; ++h) {
    if (h) __syncthreads();                  // half-0 readers done
    if (wr == h) {
      #pragma unroll
      for (int i = 0; i < 8; ++i) {
        #pragma unroll
        for (int j = 0; j < 4; ++j) {
          const int ec = wc * 64 + j * 16 + l16;
          const float bv = bias ? bias[n0 + ec] : 0.f;
          #pragma unroll
          for (int r = 0; r < 4; ++r) {
            const int r2 = i * 16 + lhi * 4 + r;   // C/D: row=(lane>>4)*4+reg
            const float val = acc[i][j][r] * scale + bv;
            Cs[r2 * 256 + 8 * ((ec >> 3) ^ (r2 & 15)) + (ec & 7)] = f2bf(val);
          }
        }
      }
    }
    __syncthreads();
    if (EPI == 0 || EPI == 2) {
      #pragma unroll
      for (int p = 0; p < 8; ++p) {
        const int id = p * 512 + t, r2 = id >> 5, cc = id & 31;
        const bf16x8 v = *(const bf16x8*)&Cs[r2 * 256 + 8 * (cc ^ (r2 & 15))];
        *(bf16x8*)(obN + (size_t)(m0 + h * 128 + r2) * ldo + n0 + cc * 8) = v;
      }
    }
    if (EPI >= 1) {
      #pragma unroll
      for (int p = 0; p < 8; ++p) {
        const int id = p * 512 + t, c = id >> 4, rs = id & 15;
        bf16x8 tv;
        #pragma unroll
        for (int jj = 0; jj < 8; ++jj) {
          const int r2 = rs * 8 + jj;
          tv[jj] = (short)Cs[r2 * 256 + 8 * ((c >> 3) ^ (r2 & 15)) + (c & 7)];
        }
        *(bf16x8*)(obT + (size_t)(n0 + c) * ldoT + m0 + h * 128 + rs * 8) = tv;
      }
    }
  }
}

// ---- wrappers -------------------------------------------------------------
// all 4 projections in one dispatch: z = proj*8 + batch
__global__ __launch_bounds__(512, 2) void gemm_proj(
    const ushort* __restrict__ x1T, const ushort* __restrict__ x2T,
    const ushort* __restrict__ wbf,
    const float* __restrict__ b_q, const float* __restrict__ b_k,
    const float* __restrict__ b_v1, const float* __restrict__ b_v2,
    ushort* __restrict__ q, ushort* __restrict__ kb,
    ushort* __restrict__ v1T, ushort* __restrict__ v2T)
{
  const int z = blockIdx.z, pj = z >> 3, b = z & 7;
  const ushort* A = ((pj & 1) ? x2T : x1T) + (size_t)b * SQ;
  const ushort* B = wbf + (size_t)pj * (C_DIM * C_DIM);
  const float* bias = pj == 0 ? b_q : pj == 1 ? b_k : pj == 2 ? b_v1 : b_v2;
  const int EPI = (pj < 2) ? 0 : 1;
  ushort* oN = (pj == 0 ? q : kb) + (size_t)b * SQ;
  ushort* oT = (pj == 2 ? v1T : v2T) + (size_t)b * SQ;
  gemm_core256(A, B, bias, EPI == 0 ? oN : nullptr, EPI == 1 ? oT : nullptr,
               C_DIM, C_DIM, C_DIM, C_DIM, L_DIM,
               blockIdx.x * 256, blockIdx.y * 256, 1.0f, EPI);
}

// attn = q.k^T * iscale -> attn AND attnT (z = batch)
__global__ __launch_bounds__(512, 2) void gemm_qkt(
    const ushort* __restrict__ qb, const ushort* __restrict__ kb,
    ushort* __restrict__ attn, ushort* __restrict__ attnT, const float scale)
{
  const int z = blockIdx.z;
  gemm_core256(qb + (size_t)z * SQ, kb + (size_t)z * SQ, nullptr,
               attn + (size_t)z * SAT, attnT + (size_t)z * SAT,
               C_DIM, C_DIM, C_DIM, L_DIM, L_DIM,
               blockIdx.x * 256, blockIdx.y * 256, scale, 2);
}

// both PVs in one dispatch: z = batch*2 + which (0: vk=P.v2, 1: vq=P^T.v1)
__global__ __launch_bounds__(512, 2) void gemm_pv(
    const ushort* __restrict__ attn, const ushort* __restrict__ attnT,
    const ushort* __restrict__ v1T, const ushort* __restrict__ v2T,
    ushort* __restrict__ vk, ushort* __restrict__ vq)
{
  const int z = blockIdx.z, b = z >> 1, which = z & 1;
  const ushort* A = (which ? attnT : attn) + (size_t)b * SAT;
  const ushort* B = (which ? v1T : v2T) + (size_t)b * SQ;
  ushort* o = (which ? vq : vk) + (size_t)b * SQ;
  gemm_core256(A, B, nullptr, o, nullptr,
               L_DIM, L_DIM, L_DIM, C_DIM, 0,
               blockIdx.x * 256, blockIdx.y * 256, 1.0f, 0);
}

// ---------------------------------------------------------------------------
// In-place row softmax over a bf16 [rows][2048] matrix (one block per row).
// ---------------------------------------------------------------------------
__global__ __launch_bounds__(256) void softmax_rows(ushort* __restrict__ attn)
{
  __shared__ float red[8];
  const int b = blockIdx.y, qi = blockIdx.x, t = threadIdx.x;
  ushort* row = attn + ((size_t)b * L_DIM + qi) * L_DIM;
  bf16x8 v = *(const bf16x8*)&row[t * 8];
  float f[8];
  #pragma unroll
  for (int j = 0; j < 8; ++j) f[j] = bf2f((ushort)v[j]);
  float m = f[0];
  #pragma unroll
  for (int j = 1; j < 8; ++j) m = fmaxf(m, f[j]);
  m = wave_red_max(m);
  if ((t & 63) == 0) red[t >> 6] = m;
  __syncthreads();
  m = fmaxf(fmaxf(red[0], red[1]), fmaxf(red[2], red[3]));
  float s = 0.f;
  #pragma unroll
  for (int j = 0; j < 8; ++j) { f[j] = __expf(f[j] - m); s += f[j]; }
  s = wave_red_sum(s);
  if ((t & 63) == 0) red[4 + (t >> 6)] = s;
  __syncthreads();
  const float inv = 1.0f / (red[4] + red[5] + red[6] + red[7]);
  bf16x8 o;
  #pragma unroll
  for (int j = 0; j < 8; ++j) o[j] = (short)f2bf(f[j] * inv);
  *(bf16x8*)&row[t * 8] = o;
}

// ---------------------------------------------------------------------------
// x [B][C][L] fp32 -> xT [B][L][C] bf16 (64x64 LDS tile transpose)
// ---------------------------------------------------------------------------
__global__ __launch_bounds__(256) void xpose(const float* __restrict__ x,
                                             ushort* __restrict__ xT)
{
  __shared__ float s[64][65];
  const int b = blockIdx.z, l0 = blockIdx.x * 64, c0 = blockIdx.y * 64;
  const int t = threadIdx.x;
  const float* xb = x + ((size_t)b * C_DIM + c0) * L_DIM + l0;
  #pragma unroll
  for (int p = 0; p < 16; ++p) {
    const int c = p * 4 + (t >> 6);
    s[c][t & 63] = xb[(size_t)c * L_DIM + (t & 63)];
  }
  __syncthreads();
  ushort* ob = xT + ((size_t)b * L_DIM + l0) * C_DIM + c0;
  #pragma unroll
  for (int p = 0; p < 16; ++p) {
    const int l = p * 4 + (t >> 6);
    ob[(size_t)l * C_DIM + (t & 63)] = f2bf(s[t & 63][l]);
  }
}

__global__ __launch_bounds__(256) void cvtw(const float* __restrict__ w,
                                            ushort* __restrict__ o)
{
  const int i = blockIdx.x * 256 + threadIdx.x;
  o[i] = f2bf(w[i]);
}

// ---------------------------------------------------------------------------
// LayerNorm over C + cross skip + transpose back to (B, C, L). vx is bf16.
// ---------------------------------------------------------------------------
__global__ __launch_bounds__(256) void ln_out(const ushort* __restrict__ vx,
    const float* __restrict__ xo, const float* __restrict__ gamma,
    const float* __restrict__ beta, float* __restrict__ out)
{
  __shared__ float s[16][513];
  __shared__ float mu[16], rsd[16];
  __shared__ float gb[512], bb[512];
  const int t = threadIdx.x;
  const int b = blockIdx.y, l0 = blockIdx.x * 16;
  #pragma unroll
  for (int r = 0; r < 2; ++r) { gb[r * 256 + t] = gamma[r * 256 + t]; bb[r * 256 + t] = beta[r * 256 + t]; }
  const ushort* vb = vx + ((size_t)b * L_DIM + l0) * C_DIM;
  #pragma unroll
  for (int p = 0; p < 4; ++p) {
    const int id = p * 256 + t;
    const int l = id >> 6, cb = (id & 63) * 8;
    bf16x8 v = *(const bf16x8*)&vb[(size_t)l * C_DIM + cb];
    #pragma unroll
    for (int j = 0; j < 8; ++j) s[l][cb + j] = bf2f((ushort)v[j]);
  }
  __syncthreads();
  const float* xb = xo + (size_t)b * C_DIM * L_DIM + l0;
  for (int it = 0; it < 32; ++it) {
    const int idx = it * 256 + t, c = idx >> 4, l = idx & 15;
    s[l][c] += xb[(size_t)c * L_DIM + l];
  }
  __syncthreads();
  const int w = t >> 6, lane = t & 63;
  #pragma unroll
  for (int rr = 0; rr < 4; ++rr) {
    const int l = w * 4 + rr;
    float sum = 0.f, sq = 0.f;
    #pragma unroll
    for (int c0 = 0; c0 < 512; c0 += 64) {
      const float v = s[l][c0 + lane];
      sum += v; sq = fmaf(v, v, sq);
    }
    sum = wave_red_sum(sum); sq = wave_red_sum(sq);
    if (lane == 0) {
      const float m = sum * (1.f / 512.f);
      const float var = sq * (1.f / 512.f) - m * m;
      mu[l] = m; rsd[l] = rsqrtf(var + 1e-5f);
    }
  }
  __syncthreads();
  float* ob = out + (size_t)b * C_DIM * L_DIM + l0;
  for (int it = 0; it < 32; ++it) {
    const int idx = it * 256 + t, c = idx >> 4, l = idx & 15;
    const float v = (s[l][c] - mu[l]) * rsd[l] * gb[c] + bb[c];
    ob[(size_t)c * L_DIM + l] = v;
  }
}

// ---------------------------------------------------------------------------
extern "C" void kernel_launch(void* const* d_in, const int* in_sizes, int n_in,
                              void* d_out, int out_size, void* d_ws, size_t ws_size,
                              hipStream_t stream) {
  const float* x1   = (const float*)d_in[0];
  const float* x2   = (const float*)d_in[1];
  const float* w_q  = (const float*)d_in[2];
  const float* b_q  = (const float*)d_in[3];
  const float* w_k  = (const float*)d_in[4];
  const float* b_k  = (const float*)d_in[5];
  const float* w_v1 = (const float*)d_in[6];
  const float* b_v1 = (const float*)d_in[7];
  const float* w_v2 = (const float*)d_in[8];
  const float* b_v2 = (const float*)d_in[9];
  const float* gamma= (const float*)d_in[10];
  const float* beta = (const float*)d_in[11];
  float* out = (float*)d_out;

  const size_t MC = (size_t)B_DIM * L_DIM * C_DIM;   // 8,388,608

  // ---- ws: exactly 128 MiB bf16 ----
  ushort* q    = (ushort*)d_ws;        // 16 MiB
  ushort* kbuf = q + MC;               // 16 MiB
  ushort* v1T  = kbuf + MC;            // 16 MiB  [C][L] per batch
  ushort* v2T  = v1T + MC;             // 16 MiB
  ushort* attn = v2T + MC;             // 64 MiB  [q][k] per batch
  // overlays in the not-yet-written attn region (dead before QK^T):
  ushort* x1T = attn;                  // 16 MiB  [B][L][C]
  ushort* x2T = attn + MC;             // 16 MiB
  ushort* wbf = attn + 2 * MC;         // 4 x 256K = 2 MiB (q|k|v1|v2)
  // PV outputs in regions dead after QK^T (q and kbuf):
  ushort* vkbuf = kbuf;
  ushort* vqbuf = q;
  // attnT [k][q] bf16 fills d_out (64 MiB), dead before ln writes:
  ushort* attnT = (ushort*)d_out;

  const float iscale = 0.044194173824159216f;  // 1/sqrt(512)
  const dim3 blk256(256), blk512(512);

  // 1) weights fp32 -> bf16
  cvtw<<<1024, blk256, 0, stream>>>(w_q,  wbf);
  cvtw<<<1024, blk256, 0, stream>>>(w_k,  wbf + 262144);
  cvtw<<<1024, blk256, 0, stream>>>(w_v1, wbf + 524288);
  cvtw<<<1024, blk256, 0, stream>>>(w_v2, wbf + 786432);
  // 2) x -> xT bf16
  xpose<<<dim3(32, 8, 8), blk256, 0, stream>>>(x1, x1T);
  xpose<<<dim3(32, 8, 8), blk256, 0, stream>>>(x2, x2T);
  // 3) all 4 projections, one dispatch (z = proj*8 + batch), 512 blocks
  gemm_proj<<<dim3(8, 2, 32), blk512, 0, stream>>>(x1T, x2T, wbf,
      b_q, b_k, b_v1, b_v2, q, kbuf, v1T, v2T);
  // 4) attn = q.k^T * iscale -> attn AND attnT, 512 blocks
  gemm_qkt<<<dim3(8, 8, 8), blk512, 0, stream>>>(q, kbuf, attn, attnT, iscale);
  // 5) in-place softmax: rows of attn (over k) and rows of attnT (over q)
  softmax_rows<<<dim3(L_DIM, B_DIM), blk256, 0, stream>>>(attn);
  softmax_rows<<<dim3(L_DIM, B_DIM), blk256, 0, stream>>>(attnT);
  // 6) both PVs, one dispatch (z = batch*2 + which), 256 blocks
  gemm_pv<<<dim3(8, 2, 16), blk512, 0, stream>>>(attn, attnT, v1T, v2T, vkbuf, vqbuf);
  // 7) LN + skip + transpose back (clobbers attnT region of d_out -- now dead)
  ln_out<<<dim3(L_DIM / 16, B_DIM), blk256, 0, stream>>>(vkbuf, x1, gamma, beta, out);
  ln_out<<<dim3(L_DIM / 16, B_DIM), blk256, 0, stream>>>(vqbuf, x2, gamma, beta, out + MC);
}

// Round 7
// 316.558 us; speedup vs baseline: 1.5441x; 1.5441x over previous
//
#include <hip/hip_runtime.h>

#define L_DIM 2048
#define C_DIM 512
#define B_DIM 8

typedef __attribute__((ext_vector_type(8))) short bf16x8;   // 8 bf16 = 4 VGPR
typedef __attribute__((ext_vector_type(4))) float f32x4;    // MFMA acc

constexpr size_t SQ  = (size_t)L_DIM * C_DIM;   // per-batch q/k/v stride
constexpr size_t SAT = (size_t)L_DIM * L_DIM;   // per-batch attn stride

__device__ __forceinline__ float bf2f(ushort u) {
  union { float f; unsigned int i; } c; c.i = ((unsigned int)u) << 16; return c.f;
}
__device__ __forceinline__ ushort f2bf(float f) {
  union { float f; unsigned int i; } c; c.f = f;
  unsigned int lsb = (c.i >> 16) & 1u;
  return (ushort)((c.i + 0x7FFFu + lsb) >> 16);
}

__device__ __forceinline__ float wave_red_max(float v) {
  #pragma unroll
  for (int o = 1; o < 64; o <<= 1) v = fmaxf(v, __shfl_xor(v, o, 64));
  return v;
}
__device__ __forceinline__ float wave_red_sum(float v) {
  #pragma unroll
  for (int o = 1; o < 64; o <<= 1) v += __shfl_xor(v, o, 64);
  return v;
}

// async global->LDS, 16B per lane (dest = wave-uniform base + lane*16)
__device__ __forceinline__ void glds16(const ushort* g, ushort* l) {
  __builtin_amdgcn_global_load_lds(
      (const __attribute__((address_space(1))) void*)g,
      (__attribute__((address_space(3))) void*)l, 16, 0, 0);
}

// LDS slot functions: row-group rotation spreads 16 consecutive rows over all
// 8 bank-quads (2-way aliasing = free). Bijective in c for fixed r.
__device__ __forceinline__ int slotAB(int r, int c) {          // c = 16B chunk 0..7
  return (((c ^ (r & 7)) + (r >> 3)) & 7);
}
__device__ __forceinline__ int chAB(int r, int sl) {           // inverse: global chunk at slot sl
  return ((sl - (r >> 3)) & 7) ^ (r & 7);
}
__device__ __forceinline__ int slotC(int r, int q4) {          // q4 = c>>3 0..15 (128-col C tile)
  return ((q4 ^ (r & 15)) + (r >> 4)) & 15;
}

// XCD-chunked swizzle (T1): hardware round-robins consecutive ids over XCDs;
// this gives each XCD a contiguous chunk of logical tile ids. nwg % 8 == 0.
__device__ __forceinline__ int xcd_swz(int bid, int nwg) {
  return (bid & 7) * (nwg >> 3) + (bid >> 3);
}

// ---------------------------------------------------------------------------
// 128x128 bf16 MFMA GEMM core, D = A.B^T. BK=64, 256 thr = 4 waves (2x2),
// double-buffered LDS + prefetch-before-compute. A:[m][K](lda), B:[n][K](ldb).
// EPI: 0 row-major store (obN,ldo), 1 transposed (obT,ldoT), 2 both.
// ---------------------------------------------------------------------------
__device__ __forceinline__ void gemm_core128(
    const ushort* __restrict__ Ab, const ushort* __restrict__ Bb,
    const float* __restrict__ bias,
    ushort* __restrict__ obN, ushort* __restrict__ obT,
    const int K, const int lda, const int ldb, const int ldo, const int ldoT,
    const int m0, const int n0, const float scale, const int EPI)
{
  __shared__ __align__(16) ushort lds[32768];   // 64 KiB: buf b at b*16384 (A 8K | B 8K)

  const int t = threadIdx.x;
  const int lane = t & 63, w = t >> 6;
  const int wr = w >> 1, wc = w & 1;
  const int l16 = lane & 15, lhi = lane >> 4;
  const int lrow = lane >> 3, lsl = lane & 7;

  f32x4 acc[4][4];
  #pragma unroll
  for (int i = 0; i < 4; ++i)
    #pragma unroll
    for (int j = 0; j < 4; ++j) { f32x4 zv = {0.f, 0.f, 0.f, 0.f}; acc[i][j] = zv; }

  auto stage = [&](int buf, int k0) {
    ushort* Asb = lds + buf * 16384;
    ushort* Bsb = Asb + 8192;
    #pragma unroll
    for (int p = 0; p < 4; ++p) {
      const int rbase = w * 32 + p * 8;
      const int rr = rbase + lrow;
      const int ch = chAB(rr, lsl);          // inverse-swizzled global source
      glds16(Ab + (size_t)(m0 + rr) * lda + k0 + ch * 8, Asb + rbase * 64);
      glds16(Bb + (size_t)(n0 + rr) * ldb + k0 + ch * 8, Bsb + rbase * 64);
    }
  };

  const int KT = K >> 6;
  stage(0, 0);
  __syncthreads();                           // drains vmcnt -> buf0 ready
  int cur = 0;
  for (int kt = 0; kt < KT; ++kt) {
    if (kt + 1 < KT) stage(cur ^ 1, (kt + 1) << 6);   // flies under compute
    const ushort* Asb = lds + cur * 16384;
    const ushort* Bsb = Asb + 8192;
    #pragma unroll
    for (int ks = 0; ks < 2; ++ks) {
      bf16x8 af[4], bg[4];
      #pragma unroll
      for (int i = 0; i < 4; ++i) {
        const int ra = wr * 64 + i * 16 + l16;
        af[i] = *(const bf16x8*)&Asb[ra * 64 + 8 * slotAB(ra, ks * 4 + lhi)];
        const int rb = wc * 64 + i * 16 + l16;
        bg[i] = *(const bf16x8*)&Bsb[rb * 64 + 8 * slotAB(rb, ks * 4 + lhi)];
      }
      #pragma unroll
      for (int i = 0; i < 4; ++i)
        #pragma unroll
        for (int j = 0; j < 4; ++j)
          acc[i][j] = __builtin_amdgcn_mfma_f32_16x16x32_bf16(af[i], bg[j], acc[i][j], 0, 0, 0);
    }
    __syncthreads();   // all waves done with buf[cur]; prefetch landed
    cur ^= 1;
  }

  // ---- epilogue: bounce C tile (128x128 bf16) through swizzled LDS ----
  ushort* Cs = lds;                          // 32 KiB
  #pragma unroll
  for (int i = 0; i < 4; ++i) {
    #pragma unroll
    for (int j = 0; j < 4; ++j) {
      const int er = wr * 64 + i * 16 + lhi * 4;       // C/D: row=(lane>>4)*4+reg
      const int ec = wc * 64 + j * 16 + l16;           //      col=lane&15
      const float bv = bias ? bias[n0 + ec] : 0.f;
      #pragma unroll
      for (int r = 0; r < 4; ++r) {
        const int rr = er + r;
        const float val = acc[i][j][r] * scale + bv;
        Cs[rr * 128 + 8 * slotC(rr, ec >> 3) + (ec & 7)] = f2bf(val);
      }
    }
  }
  __syncthreads();
  if (EPI == 0 || EPI == 2) {
    #pragma unroll
    for (int p = 0; p < 8; ++p) {
      const int id = p * 256 + t, r = id >> 4, cc = id & 15;
      const bf16x8 v = *(const bf16x8*)&Cs[r * 128 + 8 * slotC(r, cc)];
      *(bf16x8*)(obN + (size_t)(m0 + r) * ldo + n0 + cc * 8) = v;
    }
  }
  if (EPI >= 1) {
    #pragma unroll
    for (int p = 0; p < 8; ++p) {
      const int id = p * 256 + t, c = id >> 4, rs = id & 15;
      bf16x8 tv;
      #pragma unroll
      for (int jj = 0; jj < 8; ++jj) {
        const int r2 = rs * 8 + jj;
        tv[jj] = (short)Cs[r2 * 128 + 8 * slotC(r2, c >> 3) + (c & 7)];
      }
      *(bf16x8*)(obT + (size_t)(n0 + c) * ldoT + m0 + rs * 8) = tv;
    }
  }
}

// ---- wrappers (1D grids + XCD swizzle) -------------------------------------
// all 4 projections: lid = x(16) | y(4) | b(8) | pj(4)
__global__ __launch_bounds__(256) void gemm_proj(
    const ushort* __restrict__ x1T, const ushort* __restrict__ x2T,
    const ushort* __restrict__ wbf,
    const float* __restrict__ b_q, const float* __restrict__ b_k,
    const float* __restrict__ b_v1, const float* __restrict__ b_v2,
    ushort* __restrict__ q, ushort* __restrict__ kb,
    ushort* __restrict__ v1T, ushort* __restrict__ v2T)
{
  const int lid = xcd_swz(blockIdx.x, 2048);
  const int x = lid & 15, y = (lid >> 4) & 3, rest = lid >> 6;
  const int b = rest & 7, pj = rest >> 3;
  const ushort* A = ((pj & 1) ? x2T : x1T) + (size_t)b * SQ;
  const ushort* B = wbf + (size_t)pj * (C_DIM * C_DIM);
  const float* bias = pj == 0 ? b_q : pj == 1 ? b_k : pj == 2 ? b_v1 : b_v2;
  if (pj < 2) {
    ushort* oN = (pj == 0 ? q : kb) + (size_t)b * SQ;
    gemm_core128(A, B, bias, oN, nullptr, C_DIM, C_DIM, C_DIM, C_DIM, 0,
                 x * 128, y * 128, 1.0f, 0);
  } else {
    ushort* oT = (pj == 2 ? v1T : v2T) + (size_t)b * SQ;
    gemm_core128(A, B, bias, nullptr, oT, C_DIM, C_DIM, C_DIM, 0, L_DIM,
                 x * 128, y * 128, 1.0f, 1);
  }
}

// attn = q.k^T * scale -> attn AND attnT: lid = x(16) | y(16) | b(8)
__global__ __launch_bounds__(256) void gemm_qkt(
    const ushort* __restrict__ qb, const ushort* __restrict__ kb,
    ushort* __restrict__ attn, ushort* __restrict__ attnT, const float scale)
{
  const int lid = xcd_swz(blockIdx.x, 2048);
  const int x = lid & 15, y = (lid >> 4) & 15, b = lid >> 8;
  gemm_core128(qb + (size_t)b * SQ, kb + (size_t)b * SQ, nullptr,
               attn + (size_t)b * SAT, attnT + (size_t)b * SAT,
               C_DIM, C_DIM, C_DIM, L_DIM, L_DIM,
               x * 128, y * 128, scale, 2);
}

// both PVs: lid = x(16) | y(4) | which(2) | b(8)
__global__ __launch_bounds__(256) void gemm_pv(
    const ushort* __restrict__ attn, const ushort* __restrict__ attnT,
    const ushort* __restrict__ v1T, const ushort* __restrict__ v2T,
    ushort* __restrict__ vk, ushort* __restrict__ vq)
{
  const int lid = xcd_swz(blockIdx.x, 1024);
  const int x = lid & 15, y = (lid >> 4) & 3, rest = lid >> 6;
  const int which = rest & 1, b = rest >> 1;
  const ushort* A = (which ? attnT : attn) + (size_t)b * SAT;
  const ushort* B = (which ? v1T : v2T) + (size_t)b * SQ;
  ushort* o = (which ? vq : vk) + (size_t)b * SQ;
  gemm_core128(A, B, nullptr, o, nullptr,
               L_DIM, L_DIM, L_DIM, C_DIM, 0,
               x * 128, y * 128, 1.0f, 0);
}

// ---------------------------------------------------------------------------
// In-place row softmax over bf16 [rows][2048]; z selects attn / attnT.
// ---------------------------------------------------------------------------
__global__ __launch_bounds__(256) void softmax_rows(ushort* __restrict__ attn,
                                                    ushort* __restrict__ attnT)
{
  __shared__ float red[8];
  const int b = blockIdx.y, qi = blockIdx.x, t = threadIdx.x;
  ushort* base = blockIdx.z ? attnT : attn;
  ushort* row = base + ((size_t)b * L_DIM + qi) * L_DIM;
  bf16x8 v = *(const bf16x8*)&row[t * 8];
  float f[8];
  #pragma unroll
  for (int j = 0; j < 8; ++j) f[j] = bf2f((ushort)v[j]);
  float m = f[0];
  #pragma unroll
  for (int j = 1; j < 8; ++j) m = fmaxf(m, f[j]);
  m = wave_red_max(m);
  if ((t & 63) == 0) red[t >> 6] = m;
  __syncthreads();
  m = fmaxf(fmaxf(red[0], red[1]), fmaxf(red[2], red[3]));
  float s = 0.f;
  #pragma unroll
  for (int j = 0; j < 8; ++j) { f[j] = __expf(f[j] - m); s += f[j]; }
  s = wave_red_sum(s);
  if ((t & 63) == 0) red[4 + (t >> 6)] = s;
  __syncthreads();
  const float inv = 1.0f / (red[4] + red[5] + red[6] + red[7]);
  bf16x8 o;
  #pragma unroll
  for (int j = 0; j < 8; ++j) o[j] = (short)f2bf(f[j] * inv);
  *(bf16x8*)&row[t * 8] = o;
}

// ---------------------------------------------------------------------------
// x [B][C][L] fp32 -> xT [B][L][C] bf16 (64x64 LDS tile transpose)
// ---------------------------------------------------------------------------
__global__ __launch_bounds__(256) void xpose(const float* __restrict__ x,
                                             ushort* __restrict__ xT)
{
  __shared__ float s[64][65];
  const int b = blockIdx.z, l0 = blockIdx.x * 64, c0 = blockIdx.y * 64;
  const int t = threadIdx.x;
  const float* xb = x + ((size_t)b * C_DIM + c0) * L_DIM + l0;
  #pragma unroll
  for (int p = 0; p < 16; ++p) {
    const int c = p * 4 + (t >> 6);
    s[c][t & 63] = xb[(size_t)c * L_DIM + (t & 63)];
  }
  __syncthreads();
  ushort* ob = xT + ((size_t)b * L_DIM + l0) * C_DIM + c0;
  #pragma unroll
  for (int p = 0; p < 16; ++p) {
    const int l = p * 4 + (t >> 6);
    ob[(size_t)l * C_DIM + (t & 63)] = f2bf(s[t & 63][l]);
  }
}

__global__ __launch_bounds__(256) void cvtw(const float* __restrict__ w,
                                            ushort* __restrict__ o)
{
  const int i = blockIdx.x * 256 + threadIdx.x;
  o[i] = f2bf(w[i]);
}

// ---------------------------------------------------------------------------
// LayerNorm over C + cross skip + transpose back to (B, C, L). vx is bf16.
// ---------------------------------------------------------------------------
__global__ __launch_bounds__(256) void ln_out(const ushort* __restrict__ vx,
    const float* __restrict__ xo, const float* __restrict__ gamma,
    const float* __restrict__ beta, float* __restrict__ out)
{
  __shared__ float s[16][513];
  __shared__ float mu[16], rsd[16];
  __shared__ float gb[512], bb[512];
  const int t = threadIdx.x;
  const int b = blockIdx.y, l0 = blockIdx.x * 16;
  #pragma unroll
  for (int r = 0; r < 2; ++r) { gb[r * 256 + t] = gamma[r * 256 + t]; bb[r * 256 + t] = beta[r * 256 + t]; }
  const ushort* vb = vx + ((size_t)b * L_DIM + l0) * C_DIM;
  #pragma unroll
  for (int p = 0; p < 4; ++p) {
    const int id = p * 256 + t;
    const int l = id >> 6, cb = (id & 63) * 8;
    bf16x8 v = *(const bf16x8*)&vb[(size_t)l * C_DIM + cb];
    #pragma unroll
    for (int j = 0; j < 8; ++j) s[l][cb + j] = bf2f((ushort)v[j]);
  }
  __syncthreads();
  const float* xb = xo + (size_t)b * C_DIM * L_DIM + l0;
  for (int it = 0; it < 32; ++it) {
    const int idx = it * 256 + t, c = idx >> 4, l = idx & 15;
    s[l][c] += xb[(size_t)c * L_DIM + l];
  }
  __syncthreads();
  const int w = t >> 6, lane = t & 63;
  #pragma unroll
  for (int rr = 0; rr < 4; ++rr) {
    const int l = w * 4 + rr;
    float sum = 0.f, sq = 0.f;
    #pragma unroll
    for (int c0 = 0; c0 < 512; c0 += 64) {
      const float v = s[l][c0 + lane];
      sum += v; sq = fmaf(v, v, sq);
    }
    sum = wave_red_sum(sum); sq = wave_red_sum(sq);
    if (lane == 0) {
      const float m = sum * (1.f / 512.f);
      const float var = sq * (1.f / 512.f) - m * m;
      mu[l] = m; rsd[l] = rsqrtf(var + 1e-5f);
    }
  }
  __syncthreads();
  float* ob = out + (size_t)b * C_DIM * L_DIM + l0;
  for (int it = 0; it < 32; ++it) {
    const int idx = it * 256 + t, c = idx >> 4, l = idx & 15;
    const float v = (s[l][c] - mu[l]) * rsd[l] * gb[c] + bb[c];
    ob[(size_t)c * L_DIM + l] = v;
  }
}

// ---------------------------------------------------------------------------
extern "C" void kernel_launch(void* const* d_in, const int* in_sizes, int n_in,
                              void* d_out, int out_size, void* d_ws, size_t ws_size,
                              hipStream_t stream) {
  const float* x1   = (const float*)d_in[0];
  const float* x2   = (const float*)d_in[1];
  const float* w_q  = (const float*)d_in[2];
  const float* b_q  = (const float*)d_in[3];
  const float* w_k  = (const float*)d_in[4];
  const float* b_k  = (const float*)d_in[5];
  const float* w_v1 = (const float*)d_in[6];
  const float* b_v1 = (const float*)d_in[7];
  const float* w_v2 = (const float*)d_in[8];
  const float* b_v2 = (const float*)d_in[9];
  const float* gamma= (const float*)d_in[10];
  const float* beta = (const float*)d_in[11];
  float* out = (float*)d_out;

  const size_t MC = (size_t)B_DIM * L_DIM * C_DIM;   // 8,388,608

  // ---- ws: exactly 128 MiB bf16 ----
  ushort* q    = (ushort*)d_ws;        // 16 MiB
  ushort* kbuf = q + MC;               // 16 MiB
  ushort* v1T  = kbuf + MC;            // 16 MiB  [C][L] per batch
  ushort* v2T  = v1T + MC;             // 16 MiB
  ushort* attn = v2T + MC;             // 64 MiB  [q][k] per batch
  // overlays in the not-yet-written attn region (dead before QK^T):
  ushort* x1T = attn;                  // 16 MiB  [B][L][C]
  ushort* x2T = attn + MC;             // 16 MiB
  ushort* wbf = attn + 2 * MC;         // 4 x 256K = 2 MiB (q|k|v1|v2)
  // PV outputs in regions dead after QK^T:
  ushort* vkbuf = kbuf;
  ushort* vqbuf = q;
  // attnT [k][q] bf16 fills d_out (64 MiB), dead before ln writes:
  ushort* attnT = (ushort*)d_out;

  const float iscale = 0.044194173824159216f;  // 1/sqrt(512)
  const dim3 blk256(256);

  // 1) weights fp32 -> bf16
  cvtw<<<1024, blk256, 0, stream>>>(w_q,  wbf);
  cvtw<<<1024, blk256, 0, stream>>>(w_k,  wbf + 262144);
  cvtw<<<1024, blk256, 0, stream>>>(w_v1, wbf + 524288);
  cvtw<<<1024, blk256, 0, stream>>>(w_v2, wbf + 786432);
  // 2) x -> xT bf16
  xpose<<<dim3(32, 8, 8), blk256, 0, stream>>>(x1, x1T);
  xpose<<<dim3(32, 8, 8), blk256, 0, stream>>>(x2, x2T);
  // 3) all 4 projections in one dispatch
  gemm_proj<<<2048, blk256, 0, stream>>>(x1T, x2T, wbf,
      b_q, b_k, b_v1, b_v2, q, kbuf, v1T, v2T);
  // 4) attn = q.k^T * iscale -> attn AND attnT
  gemm_qkt<<<2048, blk256, 0, stream>>>(q, kbuf, attn, attnT, iscale);
  // 5) in-place softmax over rows of attn (z=0) and attnT (z=1)
  softmax_rows<<<dim3(L_DIM, B_DIM, 2), blk256, 0, stream>>>(attn, attnT);
  // 6) both PVs in one dispatch
  gemm_pv<<<1024, blk256, 0, stream>>>(attn, attnT, v1T, v2T, vkbuf, vqbuf);
  // 7) LN + skip + transpose back (clobbers attnT region of d_out -- now dead)
  ln_out<<<dim3(L_DIM / 16, B_DIM), blk256, 0, stream>>>(vkbuf, x1, gamma, beta, out);
  ln_out<<<dim3(L_DIM / 16, B_DIM), blk256, 0, stream>>>(vqbuf, x2, gamma, beta, out + MC);
}

// Round 8
// 285.016 us; speedup vs baseline: 1.7149x; 1.1107x over previous
//
#include <hip/hip_runtime.h>

#define L_DIM 2048
#define C_DIM 512
#define B_DIM 8

typedef __attribute__((ext_vector_type(8))) short bf16x8;   // 8 bf16 = 4 VGPR
typedef __attribute__((ext_vector_type(4))) float f32x4;    // MFMA acc

constexpr size_t SQ  = (size_t)L_DIM * C_DIM;   // per-batch q/k/v stride
constexpr size_t SAT = (size_t)L_DIM * L_DIM;   // per-batch attn stride
constexpr size_t MC  = (size_t)B_DIM * L_DIM * C_DIM;

__device__ __forceinline__ float bf2f(ushort u) {
  union { float f; unsigned int i; } c; c.i = ((unsigned int)u) << 16; return c.f;
}
__device__ __forceinline__ ushort f2bf(float f) {
  union { float f; unsigned int i; } c; c.f = f;
  unsigned int lsb = (c.i >> 16) & 1u;
  return (ushort)((c.i + 0x7FFFu + lsb) >> 16);
}

__device__ __forceinline__ float wave_red_max(float v) {
  #pragma unroll
  for (int o = 1; o < 64; o <<= 1) v = fmaxf(v, __shfl_xor(v, o, 64));
  return v;
}
__device__ __forceinline__ float wave_red_sum(float v) {
  #pragma unroll
  for (int o = 1; o < 64; o <<= 1) v += __shfl_xor(v, o, 64);
  return v;
}

// async global->LDS, 16B per lane (dest = wave-uniform base + lane*16)
__device__ __forceinline__ void glds16(const ushort* g, ushort* l) {
  __builtin_amdgcn_global_load_lds(
      (const __attribute__((address_space(1))) void*)g,
      (__attribute__((address_space(3))) void*)l, 16, 0, 0);
}

// LDS slot functions: row-group rotation spreads 16 consecutive rows over all
// 8 bank-quads (2-way aliasing = free). Bijective in c for fixed r.
__device__ __forceinline__ int slotAB(int r, int c) {          // c = 16B chunk 0..7
  return (((c ^ (r & 7)) + (r >> 3)) & 7);
}
__device__ __forceinline__ int chAB(int r, int sl) {           // inverse: global chunk at slot sl
  return ((sl - (r >> 3)) & 7) ^ (r & 7);
}
__device__ __forceinline__ int slotC(int r, int q4) {          // q4 = c>>3 0..15 (128-col C tile)
  return ((q4 ^ (r & 15)) + (r >> 4)) & 15;
}

// XCD-chunked swizzle (T1). nwg % 8 == 0.
__device__ __forceinline__ int xcd_swz(int bid, int nwg) {
  return (bid & 7) * (nwg >> 3) + (bid >> 3);
}

// ---------------------------------------------------------------------------
// 128x128 bf16 MFMA GEMM core, D = A.B^T. BK=64, 256 thr = 4 waves (2x2).
// SINGLE-buffered 32 KiB LDS (m97 structure): stage; barrier; compute; barrier.
// Latency hidden by ~4 blocks/CU TLP; fragment LDS addresses loop-invariant.
// EPI: 0 row-major store (obN,ldo), 1 transposed (obT,ldoT), 2 both.
// ---------------------------------------------------------------------------
__device__ __forceinline__ void gemm_core128(
    const ushort* __restrict__ Ab, const ushort* __restrict__ Bb,
    const float* __restrict__ bias,
    ushort* __restrict__ obN, ushort* __restrict__ obT,
    const int K, const int lda, const int ldb, const int ldo, const int ldoT,
    const int m0, const int n0, const float scale, const int EPI)
{
  __shared__ __align__(16) ushort lds[16384];   // 32 KiB: A 8K | B 8K ushorts

  const int t = threadIdx.x;
  const int lane = t & 63, w = t >> 6;
  const int wr = w >> 1, wc = w & 1;
  const int l16 = lane & 15, lhi = lane >> 4;
  const int lrow = lane >> 3, lsl = lane & 7;

  ushort* As = lds;
  ushort* Bs = lds + 8192;

  f32x4 acc[4][4];
  #pragma unroll
  for (int i = 0; i < 4; ++i)
    #pragma unroll
    for (int j = 0; j < 4; ++j) { f32x4 zv = {0.f, 0.f, 0.f, 0.f}; acc[i][j] = zv; }

  const int KT = K >> 6;
  for (int kt = 0; kt < KT; ++kt) {
    const int k0 = kt << 6;
    __syncthreads();                       // previous compute done with LDS
    #pragma unroll
    for (int p = 0; p < 4; ++p) {
      const int rbase = w * 32 + p * 8;
      const int rr = rbase + lrow;
      const int ch = chAB(rr, lsl);        // inverse-swizzled global source
      glds16(Ab + (size_t)(m0 + rr) * lda + k0 + ch * 8, As + rbase * 64);
      glds16(Bb + (size_t)(n0 + rr) * ldb + k0 + ch * 8, Bs + rbase * 64);
    }
    __syncthreads();                       // drains vmcnt -> LDS ready
    #pragma unroll
    for (int ks = 0; ks < 2; ++ks) {
      bf16x8 af[4], bg[4];
      #pragma unroll
      for (int i = 0; i < 4; ++i) {
        const int ra = wr * 64 + i * 16 + l16;
        af[i] = *(const bf16x8*)&As[ra * 64 + 8 * slotAB(ra, ks * 4 + lhi)];
        const int rb = wc * 64 + i * 16 + l16;
        bg[i] = *(const bf16x8*)&Bs[rb * 64 + 8 * slotAB(rb, ks * 4 + lhi)];
      }
      #pragma unroll
      for (int i = 0; i < 4; ++i)
        #pragma unroll
        for (int j = 0; j < 4; ++j)
          acc[i][j] = __builtin_amdgcn_mfma_f32_16x16x32_bf16(af[i], bg[j], acc[i][j], 0, 0, 0);
    }
  }

  // ---- epilogue: bounce C tile (128x128 bf16) through swizzled LDS ----
  __syncthreads();
  ushort* Cs = lds;                        // 32 KiB
  #pragma unroll
  for (int i = 0; i < 4; ++i) {
    #pragma unroll
    for (int j = 0; j < 4; ++j) {
      const int er = wr * 64 + i * 16 + lhi * 4;       // C/D: row=(lane>>4)*4+reg
      const int ec = wc * 64 + j * 16 + l16;           //      col=lane&15
      const float bv = bias ? bias[n0 + ec] : 0.f;
      #pragma unroll
      for (int r = 0; r < 4; ++r) {
        const int rr = er + r;
        const float val = acc[i][j][r] * scale + bv;
        Cs[rr * 128 + 8 * slotC(rr, ec >> 3) + (ec & 7)] = f2bf(val);
      }
    }
  }
  __syncthreads();
  if (EPI == 0 || EPI == 2) {
    #pragma unroll
    for (int p = 0; p < 8; ++p) {
      const int id = p * 256 + t, r = id >> 4, cc = id & 15;
      const bf16x8 v = *(const bf16x8*)&Cs[r * 128 + 8 * slotC(r, cc)];
      *(bf16x8*)(obN + (size_t)(m0 + r) * ldo + n0 + cc * 8) = v;
    }
  }
  if (EPI >= 1) {
    #pragma unroll
    for (int p = 0; p < 8; ++p) {
      const int id = p * 256 + t, c = id >> 4, rs = id & 15;
      bf16x8 tv;
      #pragma unroll
      for (int jj = 0; jj < 8; ++jj) {
        const int r2 = rs * 8 + jj;
        tv[jj] = (short)Cs[r2 * 128 + 8 * slotC(r2, c >> 3) + (c & 7)];
      }
      *(bf16x8*)(obT + (size_t)(n0 + c) * ldoT + m0 + rs * 8) = tv;
    }
  }
}

// ---- wrappers (1D grids + XCD swizzle) -------------------------------------
// all 4 projections: lid = x(16) | y(4) | b(8) | pj(4)
__global__ __launch_bounds__(256, 4) void gemm_proj(
    const ushort* __restrict__ x1T, const ushort* __restrict__ x2T,
    const ushort* __restrict__ wbf,
    const float* __restrict__ b_q, const float* __restrict__ b_k,
    const float* __restrict__ b_v1, const float* __restrict__ b_v2,
    ushort* __restrict__ q, ushort* __restrict__ kb,
    ushort* __restrict__ v1T, ushort* __restrict__ v2T)
{
  const int lid = xcd_swz(blockIdx.x, 2048);
  const int x = lid & 15, y = (lid >> 4) & 3, rest = lid >> 6;
  const int b = rest & 7, pj = rest >> 3;
  const ushort* A = ((pj & 1) ? x2T : x1T) + (size_t)b * SQ;
  const ushort* B = wbf + (size_t)pj * (C_DIM * C_DIM);
  const float* bias = pj == 0 ? b_q : pj == 1 ? b_k : pj == 2 ? b_v1 : b_v2;
  if (pj < 2) {
    ushort* oN = (pj == 0 ? q : kb) + (size_t)b * SQ;
    gemm_core128(A, B, bias, oN, nullptr, C_DIM, C_DIM, C_DIM, C_DIM, 0,
                 x * 128, y * 128, 1.0f, 0);
  } else {
    ushort* oT = (pj == 2 ? v1T : v2T) + (size_t)b * SQ;
    gemm_core128(A, B, bias, nullptr, oT, C_DIM, C_DIM, C_DIM, 0, L_DIM,
                 x * 128, y * 128, 1.0f, 1);
  }
}

// attn = q.k^T * scale -> attn AND attnT: lid = x(16) | y(16) | b(8)
__global__ __launch_bounds__(256, 4) void gemm_qkt(
    const ushort* __restrict__ qb, const ushort* __restrict__ kb,
    ushort* __restrict__ attn, ushort* __restrict__ attnT, const float scale)
{
  const int lid = xcd_swz(blockIdx.x, 2048);
  const int x = lid & 15, y = (lid >> 4) & 15, b = lid >> 8;
  gemm_core128(qb + (size_t)b * SQ, kb + (size_t)b * SQ, nullptr,
               attn + (size_t)b * SAT, attnT + (size_t)b * SAT,
               C_DIM, C_DIM, C_DIM, L_DIM, L_DIM,
               x * 128, y * 128, scale, 2);
}

// both PVs: lid = x(16) | y(4) | which(2) | b(8)
__global__ __launch_bounds__(256, 4) void gemm_pv(
    const ushort* __restrict__ attn, const ushort* __restrict__ attnT,
    const ushort* __restrict__ v1T, const ushort* __restrict__ v2T,
    ushort* __restrict__ vk, ushort* __restrict__ vq)
{
  const int lid = xcd_swz(blockIdx.x, 1024);
  const int x = lid & 15, y = (lid >> 4) & 3, rest = lid >> 6;
  const int which = rest & 1, b = rest >> 1;
  const ushort* A = (which ? attnT : attn) + (size_t)b * SAT;
  const ushort* B = (which ? v1T : v2T) + (size_t)b * SQ;
  ushort* o = (which ? vq : vk) + (size_t)b * SQ;
  gemm_core128(A, B, nullptr, o, nullptr,
               L_DIM, L_DIM, L_DIM, C_DIM, 0,
               x * 128, y * 128, 1.0f, 0);
}

// ---------------------------------------------------------------------------
// In-place row softmax over bf16 [rows][2048]; z selects attn / attnT.
// ---------------------------------------------------------------------------
__global__ __launch_bounds__(256) void softmax_rows(ushort* __restrict__ attn,
                                                    ushort* __restrict__ attnT)
{
  __shared__ float red[8];
  const int b = blockIdx.y, qi = blockIdx.x, t = threadIdx.x;
  ushort* base = blockIdx.z ? attnT : attn;
  ushort* row = base + ((size_t)b * L_DIM + qi) * L_DIM;
  bf16x8 v = *(const bf16x8*)&row[t * 8];
  float f[8];
  #pragma unroll
  for (int j = 0; j < 8; ++j) f[j] = bf2f((ushort)v[j]);
  float m = f[0];
  #pragma unroll
  for (int j = 1; j < 8; ++j) m = fmaxf(m, f[j]);
  m = wave_red_max(m);
  if ((t & 63) == 0) red[t >> 6] = m;
  __syncthreads();
  m = fmaxf(fmaxf(red[0], red[1]), fmaxf(red[2], red[3]));
  float s = 0.f;
  #pragma unroll
  for (int j = 0; j < 8; ++j) { f[j] = __expf(f[j] - m); s += f[j]; }
  s = wave_red_sum(s);
  if ((t & 63) == 0) red[4 + (t >> 6)] = s;
  __syncthreads();
  const float inv = 1.0f / (red[4] + red[5] + red[6] + red[7]);
  bf16x8 o;
  #pragma unroll
  for (int j = 0; j < 8; ++j) o[j] = (short)f2bf(f[j] * inv);
  *(bf16x8*)&row[t * 8] = o;
}

// ---------------------------------------------------------------------------
// x [B][C][L] fp32 -> xT [B][L][C] bf16, both inputs in one dispatch:
// z 0..15 -> (src = z<8 ? x1 : x2, batch = z&7); x2T = x1T + 8*SQ.
// ---------------------------------------------------------------------------
__global__ __launch_bounds__(256) void xpose(const float* __restrict__ x1,
                                             const float* __restrict__ x2,
                                             ushort* __restrict__ xT)
{
  __shared__ float s[64][65];
  const int z = blockIdx.z, l0 = blockIdx.x * 64, c0 = blockIdx.y * 64;
  const int t = threadIdx.x;
  const float* xb = (z < 8 ? x1 : x2) + ((size_t)(z & 7) * C_DIM + c0) * L_DIM + l0;
  #pragma unroll
  for (int p = 0; p < 16; ++p) {
    const int c = p * 4 + (t >> 6);
    s[c][t & 63] = xb[(size_t)c * L_DIM + (t & 63)];
  }
  __syncthreads();
  ushort* ob = xT + (size_t)z * SQ + (size_t)l0 * C_DIM + c0;
  #pragma unroll
  for (int p = 0; p < 16; ++p) {
    const int l = p * 4 + (t >> 6);
    ob[(size_t)l * C_DIM + (t & 63)] = f2bf(s[t & 63][l]);
  }
}

// all 4 weights fp32 -> bf16 in one dispatch (grid 4096, 262144 elems each)
__global__ __launch_bounds__(256) void cvtw4(const float* __restrict__ a,
    const float* __restrict__ b, const float* __restrict__ c,
    const float* __restrict__ d, ushort* __restrict__ o)
{
  const int i = blockIdx.x * 256 + threadIdx.x;
  const int sel = i >> 18;
  const float* w = sel == 0 ? a : sel == 1 ? b : sel == 2 ? c : d;
  o[i] = f2bf(w[i & 262143]);
}

// ---------------------------------------------------------------------------
// LayerNorm over C + cross skip + transpose back to (B, C, L). Both outputs
// in one dispatch: z = 0 -> (vk, x1, out), z = 1 -> (vq, x2, out + MC).
// ---------------------------------------------------------------------------
__global__ __launch_bounds__(256) void ln_out(const ushort* __restrict__ vk,
    const ushort* __restrict__ vq, const float* __restrict__ x1,
    const float* __restrict__ x2, const float* __restrict__ gamma,
    const float* __restrict__ beta, float* __restrict__ out)
{
  __shared__ float s[16][513];
  __shared__ float mu[16], rsd[16];
  __shared__ float gb[512], bb[512];
  const int t = threadIdx.x;
  const int b = blockIdx.y, l0 = blockIdx.x * 16, which = blockIdx.z;
  const ushort* vx = which ? vq : vk;
  const float* xo = which ? x2 : x1;
  float* obase = out + (size_t)which * MC;
  #pragma unroll
  for (int r = 0; r < 2; ++r) { gb[r * 256 + t] = gamma[r * 256 + t]; bb[r * 256 + t] = beta[r * 256 + t]; }
  const ushort* vb = vx + ((size_t)b * L_DIM + l0) * C_DIM;
  #pragma unroll
  for (int p = 0; p < 4; ++p) {
    const int id = p * 256 + t;
    const int l = id >> 6, cb = (id & 63) * 8;
    bf16x8 v = *(const bf16x8*)&vb[(size_t)l * C_DIM + cb];
    #pragma unroll
    for (int j = 0; j < 8; ++j) s[l][cb + j] = bf2f((ushort)v[j]);
  }
  __syncthreads();
  const float* xb = xo + (size_t)b * C_DIM * L_DIM + l0;
  for (int it = 0; it < 32; ++it) {
    const int idx = it * 256 + t, c = idx >> 4, l = idx & 15;
    s[l][c] += xb[(size_t)c * L_DIM + l];
  }
  __syncthreads();
  const int w = t >> 6, lane = t & 63;
  #pragma unroll
  for (int rr = 0; rr < 4; ++rr) {
    const int l = w * 4 + rr;
    float sum = 0.f, sq = 0.f;
    #pragma unroll
    for (int c0 = 0; c0 < 512; c0 += 64) {
      const float v = s[l][c0 + lane];
      sum += v; sq = fmaf(v, v, sq);
    }
    sum = wave_red_sum(sum); sq = wave_red_sum(sq);
    if (lane == 0) {
      const float m = sum * (1.f / 512.f);
      const float var = sq * (1.f / 512.f) - m * m;
      mu[l] = m; rsd[l] = rsqrtf(var + 1e-5f);
    }
  }
  __syncthreads();
  float* ob = obase + (size_t)b * C_DIM * L_DIM + l0;
  for (int it = 0; it < 32; ++it) {
    const int idx = it * 256 + t, c = idx >> 4, l = idx & 15;
    const float v = (s[l][c] - mu[l]) * rsd[l] * gb[c] + bb[c];
    ob[(size_t)c * L_DIM + l] = v;
  }
}

// ---------------------------------------------------------------------------
extern "C" void kernel_launch(void* const* d_in, const int* in_sizes, int n_in,
                              void* d_out, int out_size, void* d_ws, size_t ws_size,
                              hipStream_t stream) {
  const float* x1   = (const float*)d_in[0];
  const float* x2   = (const float*)d_in[1];
  const float* w_q  = (const float*)d_in[2];
  const float* b_q  = (const float*)d_in[3];
  const float* w_k  = (const float*)d_in[4];
  const float* b_k  = (const float*)d_in[5];
  const float* w_v1 = (const float*)d_in[6];
  const float* b_v1 = (const float*)d_in[7];
  const float* w_v2 = (const float*)d_in[8];
  const float* b_v2 = (const float*)d_in[9];
  const float* gamma= (const float*)d_in[10];
  const float* beta = (const float*)d_in[11];
  float* out = (float*)d_out;

  // ---- ws: exactly 128 MiB bf16 ----
  ushort* q    = (ushort*)d_ws;        // 16 MiB
  ushort* kbuf = q + MC;               // 16 MiB
  ushort* v1T  = kbuf + MC;            // 16 MiB  [C][L] per batch
  ushort* v2T  = v1T + MC;             // 16 MiB
  ushort* attn = v2T + MC;             // 64 MiB  [q][k] per batch
  // overlays in the not-yet-written attn region (dead before QK^T):
  ushort* x1T = attn;                  // 16 MiB  [B][L][C]  (x2T = x1T + MC)
  ushort* wbf = attn + 2 * MC;         // 4 x 256K = 2 MiB (q|k|v1|v2)
  // PV outputs in regions dead after QK^T:
  ushort* vkbuf = kbuf;
  ushort* vqbuf = q;
  // attnT [k][q] bf16 fills d_out (64 MiB), dead before ln writes:
  ushort* attnT = (ushort*)d_out;

  const float iscale = 0.044194173824159216f;  // 1/sqrt(512)
  const dim3 blk256(256);

  // 1) weights fp32 -> bf16 (one dispatch)
  cvtw4<<<4096, blk256, 0, stream>>>(w_q, w_k, w_v1, w_v2, wbf);
  // 2) x1,x2 -> xT bf16 (one dispatch)
  xpose<<<dim3(32, 8, 16), blk256, 0, stream>>>(x1, x2, x1T);
  // 3) all 4 projections in one dispatch
  gemm_proj<<<2048, blk256, 0, stream>>>(x1T, x1T + MC, wbf,
      b_q, b_k, b_v1, b_v2, q, kbuf, v1T, v2T);
  // 4) attn = q.k^T * iscale -> attn AND attnT
  gemm_qkt<<<2048, blk256, 0, stream>>>(q, kbuf, attn, attnT, iscale);
  // 5) in-place softmax over rows of attn (z=0) and attnT (z=1)
  softmax_rows<<<dim3(L_DIM, B_DIM, 2), blk256, 0, stream>>>(attn, attnT);
  // 6) both PVs in one dispatch
  gemm_pv<<<1024, blk256, 0, stream>>>(attn, attnT, v1T, v2T, vkbuf, vqbuf);
  // 7) LN + skip + transpose back, both outputs (clobbers attnT -- now dead)
  ln_out<<<dim3(L_DIM / 16, B_DIM, 2), blk256, 0, stream>>>(
      vkbuf, vqbuf, x1, x2, gamma, beta, out);
}